// Round 2
// baseline (113.471 us; speedup 1.0000x reference)
//
#include <hip/hip_runtime.h>
#include <hip/hip_bf16.h>
#include <math.h>

#define D_   64
#define HW_  4096
#define N_   16384
#define M_   4096

// ---- geometry ----
#define BM 128                 // codes per block (e-rows register-resident)
#define NSPLIT 16              // n-splits across grid
#define NCHUNK (N_ / NSPLIT)   // 1024 rows per block
#define NTILES (NCHUNK / 128)  // 8 tiles of 128 rows (4 waves x 32)
#define NBLOCKS ((M_ / BM) * NSPLIT)   // 512 main blocks

// ---- ws layout (floats) ----
#define AZN_OFF 0                      // azn'[16384]  (log2-domain row norms)
#define AEN_OFF 16384                  // aen'[4096]   (log2-domain col norms)
#define SUM_OFF 20480                  // sums[4096]
#define ZTB_OFF 24576                  // zT bf16 [16384][64] = 524288 floats
#define EBF_OFF (24576 + 524288)       // e  bf16 [4096][64]  = 131072 floats
#define TICK_OFF (EBF_OFF + 131072)    // int ticket (1 float slot)
#define WS_FLOATS (TICK_OFF + 1)

#define L2E 1.4426950408889634f
#define LN2 0.6931471805599453

typedef __attribute__((ext_vector_type(8))) short short8;
typedef __attribute__((ext_vector_type(16))) float floatx16;

#if __has_builtin(__builtin_amdgcn_exp2f)
#define EXP2F(x) __builtin_amdgcn_exp2f(x)
#else
#define EXP2F(x) exp2f(x)
#endif

__device__ __forceinline__ unsigned int bf16_rne(float x) {
    unsigned int u = __float_as_uint(x);
    u += 0x7fffu + ((u >> 16) & 1u);
    return u >> 16;
}

// blocks 0..255: z transpose+scale+norm ; blocks 256..271: e convert+norm+zero sums+ticket
__global__ void prep_kernel(const float* __restrict__ z,
                            const float* __restrict__ e,
                            const float* __restrict__ lsp,
                            float* __restrict__ ws) {
    const float ls = lsp[0];
    const float alpha = -0.5f * __expf(-2.f * ls);   // -1/(2 e^{2ls})
    const float anl = alpha * L2E;                   // norm scale (log2 domain)
    const float c2p = -2.f * alpha * L2E;            // z pre-scale (log2 domain)
    unsigned short* zTb = (unsigned short*)(ws + ZTB_OFF);
    unsigned short* ebf = (unsigned short*)(ws + EBF_OFF);
    const int blk = blockIdx.x, t = threadIdx.x;

    if (blk < 256) {
        __shared__ float lt[64 * 65];
        const int b = blk >> 6, hw0 = (blk & 63) * 64;
        const int n0 = b * HW_ + hw0;
        const float* zb = z + ((size_t)b * D_) * HW_ + hw0;
#pragma unroll
        for (int i = 0; i < 4; ++i) {
            int idx = t + 256 * i;
            int d = idx >> 4, c = (idx & 15) * 4;
            float4 v = *(const float4*)(zb + (size_t)d * HW_ + c);
            float* p = &lt[d * 65 + c];
            p[0] = v.x; p[1] = v.y; p[2] = v.z; p[3] = v.w;
        }
        __syncthreads();
#pragma unroll
        for (int j = 0; j < 2; ++j) {
            int idx = t + 256 * j;
            int nl = idx >> 3, g = idx & 7;
            float v[8]; float s = 0.f;
#pragma unroll
            for (int jj = 0; jj < 8; ++jj) {
                v[jj] = lt[(8 * g + jj) * 65 + nl];
                s = fmaf(v[jj], v[jj], s);
            }
            s += __shfl_xor(s, 1);
            s += __shfl_xor(s, 2);
            s += __shfl_xor(s, 4);
            uint4 pk;
            pk.x = bf16_rne(v[0] * c2p) | (bf16_rne(v[1] * c2p) << 16);
            pk.y = bf16_rne(v[2] * c2p) | (bf16_rne(v[3] * c2p) << 16);
            pk.z = bf16_rne(v[4] * c2p) | (bf16_rne(v[5] * c2p) << 16);
            pk.w = bf16_rne(v[6] * c2p) | (bf16_rne(v[7] * c2p) << 16);
            *(uint4*)(zTb + (size_t)(n0 + nl) * 64 + 8 * g) = pk;
            if (g == 0) ws[AZN_OFF + n0 + nl] = anl * s;
        }
    } else {
        int m = (blk - 256) * 256 + t;
        const float4* ep = (const float4*)(e + (size_t)m * D_);
        float s = 0.f;
        unsigned int pk[32];
#pragma unroll
        for (int k = 0; k < 16; ++k) {
            float4 v = ep[k];
            s += v.x * v.x + v.y * v.y + v.z * v.z + v.w * v.w;
            pk[2 * k]     = bf16_rne(v.x) | (bf16_rne(v.y) << 16);
            pk[2 * k + 1] = bf16_rne(v.z) | (bf16_rne(v.w) << 16);
        }
        uint4* op = (uint4*)(ebf + (size_t)m * 64);
#pragma unroll
        for (int k = 0; k < 8; ++k)
            op[k] = make_uint4(pk[4 * k], pk[4 * k + 1], pk[4 * k + 2], pk[4 * k + 3]);
        ws[AEN_OFF + m] = anl * s;
        ws[SUM_OFF + m] = 0.f;
        if (blk == 256 && t == 0) *(int*)(ws + TICK_OFF) = 0;
    }
}

// grid (32,16), 256 thr: B (e, 128 rows) register-resident; 8 A-tiles of 128 rows
// with register double-buffer prefetch; aen factored OUT (added in last-block finalize).
// Last-arriving block (device-scope atomic ticket) performs the logsumexp finalize.
__global__ __launch_bounds__(256, 2) void main_fast(float* __restrict__ ws,
                                                    const float* __restrict__ lsp,
                                                    float* __restrict__ out) {
    __shared__ double red[256];          // finalize reduction; aliased as float[] earlier
    __shared__ int lastFlag;
    float* lds_red = (float*)red;

    const unsigned short* zTb = (const unsigned short*)(ws + ZTB_OFF);
    const unsigned short* ebf = (const unsigned short*)(ws + EBF_OFF);
    const float* azn = ws + AZN_OFF;
    float* sums = ws + SUM_OFF;

    const int m0 = blockIdx.x * BM;
    const int ns = blockIdx.y;
    const int t = threadIdx.x;
    const int lane = t & 63;
    const int w = t >> 6;
    const int rlo = lane & 31;
    const int kh = lane >> 5;

    // B fragments: 128 e-rows register-resident (64 VGPR)
    short8 bf[4][4];
#pragma unroll
    for (int mt = 0; mt < 4; ++mt) {
        int row = m0 + mt * 32 + rlo;
#pragma unroll
        for (int ks = 0; ks < 4; ++ks)
            bf[mt][ks] = *(const short8*)(ebf + (size_t)row * 64 + (ks * 2 + kh) * 8);
    }

    float sum[4] = {0.f, 0.f, 0.f, 0.f};
    const int nbase = ns * NCHUNK + w * 32;

    // prefetch tile 0
    short8 afc[4];
    float4 aznc[4];
    {
#pragma unroll
        for (int ks = 0; ks < 4; ++ks)
            afc[ks] = *(const short8*)(zTb + (size_t)(nbase + rlo) * 64 + (ks * 2 + kh) * 8);
        const int r0 = nbase + 4 * kh;
#pragma unroll
        for (int rg = 0; rg < 4; ++rg) aznc[rg] = *(const float4*)(azn + r0 + 8 * rg);
    }

#pragma unroll
    for (int tile = 0; tile < NTILES; ++tile) {
        short8 afn[4];
        float4 aznn[4];
        if (tile + 1 < NTILES) {
            const int nr = nbase + (tile + 1) * 128;
#pragma unroll
            for (int ks = 0; ks < 4; ++ks)
                afn[ks] = *(const short8*)(zTb + (size_t)(nr + rlo) * 64 + (ks * 2 + kh) * 8);
            const int r0 = nr + 4 * kh;
#pragma unroll
            for (int rg = 0; rg < 4; ++rg) aznn[rg] = *(const float4*)(azn + r0 + 8 * rg);
        }

        float azn_r[16];
#pragma unroll
        for (int rg = 0; rg < 4; ++rg) {
            azn_r[rg * 4 + 0] = aznc[rg].x; azn_r[rg * 4 + 1] = aznc[rg].y;
            azn_r[rg * 4 + 2] = aznc[rg].z; azn_r[rg * 4 + 3] = aznc[rg].w;
        }

        floatx16 acc[4];
#pragma unroll
        for (int mt = 0; mt < 4; ++mt)
#pragma unroll
            for (int r = 0; r < 16; ++r)
                acc[mt][r] = azn_r[r];           // aen factored out

#pragma unroll
        for (int ks = 0; ks < 4; ++ks)
#pragma unroll
            for (int mt = 0; mt < 4; ++mt)
                acc[mt] = __builtin_amdgcn_mfma_f32_32x32x16_bf16(
                    afc[ks], bf[mt][ks], acc[mt], 0, 0, 0);

#pragma unroll
        for (int mt = 0; mt < 4; ++mt) {
            float s = 0.f;
#pragma unroll
            for (int r = 0; r < 16; ++r) s += EXP2F(acc[mt][r]);
            sum[mt] += s;
        }

#pragma unroll
        for (int ks = 0; ks < 4; ++ks) afc[ks] = afn[ks];
#pragma unroll
        for (int rg = 0; rg < 4; ++rg) aznc[rg] = aznn[rg];
    }

#pragma unroll
    for (int mt = 0; mt < 4; ++mt) sum[mt] += __shfl_down(sum[mt], 32);

    if (t < BM) lds_red[t] = 0.f;
    __syncthreads();
    if (lane < 32) {
#pragma unroll
        for (int mt = 0; mt < 4; ++mt) atomicAdd(&lds_red[mt * 32 + rlo], sum[mt]);
    }
    __syncthreads();
    if (t < BM) atomicAdd(&sums[m0 + t], lds_red[t]);

    // ---- last-block ticket ----
    __threadfence();          // each thread: its sums atomics complete before proceeding
    __syncthreads();          // all threads of this block have fenced
    if (t == 0) {
        int old = atomicAdd((int*)(ws + TICK_OFF), 1);
        lastFlag = (old == NBLOCKS - 1);
    }
    __syncthreads();

    if (lastFlag) {
        __threadfence();
        const float* aen = ws + AEN_OFF;
        double local = 0.0;
#pragma unroll
        for (int j = 0; j < 16; ++j) {
            int m = t + 256 * j;
            float S = atomicAdd(&sums[m], 0.f);   // coherent read at memory-side point
            // lse_m = ln2 * (aen'_m + log2(S_m))
            local += (double)(aen[m] + log2f(S));
        }
        red[t] = local;
        __syncthreads();
        for (int off = 128; off > 0; off >>= 1) {
            if (t < off) red[t] += red[t + off];
            __syncthreads();
        }
        if (t == 0) {
            double ls = (double)lsp[0];
            double loss = -(LN2 * red[0] / (double)M_)
                          + 0.5 * (double)D_ * (2.0 * ls - 1.0)
                          + log((double)N_);
            out[0] = (float)loss;
        }
    }
}

extern "C" void kernel_launch(void* const* d_in, const int* in_sizes, int n_in,
                              void* d_out, int out_size, void* d_ws, size_t ws_size,
                              hipStream_t stream) {
    const float* z   = (const float*)d_in[0];
    const float* e   = (const float*)d_in[1];
    const float* lsp = (const float*)d_in[2];
    float* ws  = (float*)d_ws;
    float* out = (float*)d_out;

    hipLaunchKernelGGL(prep_kernel, dim3(272), dim3(256), 0, stream, z, e, lsp, ws);
    hipLaunchKernelGGL(main_fast, dim3(M_ / BM, NSPLIT), dim3(256), 0, stream,
                       ws, lsp, out);
}

// Round 3
// 88.185 us; speedup vs baseline: 1.2867x; 1.2867x over previous
//
#include <hip/hip_runtime.h>
#include <hip/hip_bf16.h>
#include <math.h>

#define D_   64
#define HW_  4096
#define N_   16384
#define M_   4096

// ---- geometry ----
#define BM 128                 // codes per block (e-rows register-resident)
#define NSPLIT 32              // n-splits across grid (4 blocks/CU co-resident)
#define NCHUNK (N_ / NSPLIT)   // 512 rows per block
#define NTILES (NCHUNK / 128)  // 4 tiles of 128 rows (4 waves x 32)
#define NBLOCKS ((M_ / BM) * NSPLIT)   // 1024 main blocks

// ---- ws layout (floats) ----
#define AZN_OFF 0                      // azn'[16384]  (log2-domain row norms)
#define AEN_OFF 16384                  // aen'[4096]   (log2-domain col norms)
#define SUM_OFF 20480                  // sums[4096]
#define ZTB_OFF 24576                  // zT bf16 [16384][64] = 524288 floats
#define EBF_OFF (24576 + 524288)       // e  bf16 [4096][64]  = 131072 floats
#define TICK_OFF (EBF_OFF + 131072)    // int ticket (1 float slot)
#define WS_FLOATS (TICK_OFF + 1)

#define L2E 1.4426950408889634f
#define LN2 0.6931471805599453

typedef __attribute__((ext_vector_type(8))) short short8;
typedef __attribute__((ext_vector_type(16))) float floatx16;

#if __has_builtin(__builtin_amdgcn_exp2f)
#define EXP2F(x) __builtin_amdgcn_exp2f(x)
#else
#define EXP2F(x) exp2f(x)
#endif

__device__ __forceinline__ unsigned int bf16_rne(float x) {
    unsigned int u = __float_as_uint(x);
    u += 0x7fffu + ((u >> 16) & 1u);
    return u >> 16;
}

// blocks 0..255: z transpose+scale+norm ; blocks 256..271: e convert+norm+zero sums+ticket
__global__ void prep_kernel(const float* __restrict__ z,
                            const float* __restrict__ e,
                            const float* __restrict__ lsp,
                            float* __restrict__ ws) {
    const float ls = lsp[0];
    const float alpha = -0.5f * __expf(-2.f * ls);   // -1/(2 e^{2ls})
    const float anl = alpha * L2E;                   // norm scale (log2 domain)
    const float c2p = -2.f * alpha * L2E;            // z pre-scale (log2 domain)
    unsigned short* zTb = (unsigned short*)(ws + ZTB_OFF);
    unsigned short* ebf = (unsigned short*)(ws + EBF_OFF);
    const int blk = blockIdx.x, t = threadIdx.x;

    if (blk < 256) {
        __shared__ float lt[64 * 65];
        const int b = blk >> 6, hw0 = (blk & 63) * 64;
        const int n0 = b * HW_ + hw0;
        const float* zb = z + ((size_t)b * D_) * HW_ + hw0;
#pragma unroll
        for (int i = 0; i < 4; ++i) {
            int idx = t + 256 * i;
            int d = idx >> 4, c = (idx & 15) * 4;
            float4 v = *(const float4*)(zb + (size_t)d * HW_ + c);
            float* p = &lt[d * 65 + c];
            p[0] = v.x; p[1] = v.y; p[2] = v.z; p[3] = v.w;
        }
        __syncthreads();
#pragma unroll
        for (int j = 0; j < 2; ++j) {
            int idx = t + 256 * j;
            int nl = idx >> 3, g = idx & 7;
            float v[8]; float s = 0.f;
#pragma unroll
            for (int jj = 0; jj < 8; ++jj) {
                v[jj] = lt[(8 * g + jj) * 65 + nl];
                s = fmaf(v[jj], v[jj], s);
            }
            s += __shfl_xor(s, 1);
            s += __shfl_xor(s, 2);
            s += __shfl_xor(s, 4);
            uint4 pk;
            pk.x = bf16_rne(v[0] * c2p) | (bf16_rne(v[1] * c2p) << 16);
            pk.y = bf16_rne(v[2] * c2p) | (bf16_rne(v[3] * c2p) << 16);
            pk.z = bf16_rne(v[4] * c2p) | (bf16_rne(v[5] * c2p) << 16);
            pk.w = bf16_rne(v[6] * c2p) | (bf16_rne(v[7] * c2p) << 16);
            *(uint4*)(zTb + (size_t)(n0 + nl) * 64 + 8 * g) = pk;
            if (g == 0) ws[AZN_OFF + n0 + nl] = anl * s;
        }
    } else {
        int m = (blk - 256) * 256 + t;
        const float4* ep = (const float4*)(e + (size_t)m * D_);
        float s = 0.f;
        unsigned int pk[32];
#pragma unroll
        for (int k = 0; k < 16; ++k) {
            float4 v = ep[k];
            s += v.x * v.x + v.y * v.y + v.z * v.z + v.w * v.w;
            pk[2 * k]     = bf16_rne(v.x) | (bf16_rne(v.y) << 16);
            pk[2 * k + 1] = bf16_rne(v.z) | (bf16_rne(v.w) << 16);
        }
        uint4* op = (uint4*)(ebf + (size_t)m * 64);
#pragma unroll
        for (int k = 0; k < 8; ++k)
            op[k] = make_uint4(pk[4 * k], pk[4 * k + 1], pk[4 * k + 2], pk[4 * k + 3]);
        ws[AEN_OFF + m] = anl * s;
        ws[SUM_OFF + m] = 0.f;
        if (blk == 256 && t == 0) *(int*)(ws + TICK_OFF) = 0;
    }
}

// grid (32,32), 256 thr: B (e, 128 rows) register-resident; 4 A-tiles of 128 rows
// with register double-buffer prefetch; aen factored OUT (added in last-block finalize).
// Last-arriving block (device-scope atomic ticket) performs the logsumexp finalize.
// NO __threadfence(): device-scope atomics complete at the memory-side coherent
// point and __syncthreads drains vmcnt, so ticket ordering holds without the
// L2-invalidating buffer_inv that a fence would emit.
__global__ __launch_bounds__(256, 2) void main_fast(float* __restrict__ ws,
                                                    const float* __restrict__ lsp,
                                                    float* __restrict__ out) {
    __shared__ double red[256];          // finalize reduction; aliased as float[] earlier
    __shared__ int lastFlag;
    float* lds_red = (float*)red;

    const unsigned short* zTb = (const unsigned short*)(ws + ZTB_OFF);
    const unsigned short* ebf = (const unsigned short*)(ws + EBF_OFF);
    const float* azn = ws + AZN_OFF;
    float* sums = ws + SUM_OFF;

    const int m0 = blockIdx.x * BM;
    const int ns = blockIdx.y;
    const int t = threadIdx.x;
    const int lane = t & 63;
    const int w = t >> 6;
    const int rlo = lane & 31;
    const int kh = lane >> 5;

    // B fragments: 128 e-rows register-resident (64 VGPR)
    short8 bf[4][4];
#pragma unroll
    for (int mt = 0; mt < 4; ++mt) {
        int row = m0 + mt * 32 + rlo;
#pragma unroll
        for (int ks = 0; ks < 4; ++ks)
            bf[mt][ks] = *(const short8*)(ebf + (size_t)row * 64 + (ks * 2 + kh) * 8);
    }

    float sum[4] = {0.f, 0.f, 0.f, 0.f};
    const int nbase = ns * NCHUNK + w * 32;

    // prefetch tile 0
    short8 afc[4];
    float4 aznc[4];
    {
#pragma unroll
        for (int ks = 0; ks < 4; ++ks)
            afc[ks] = *(const short8*)(zTb + (size_t)(nbase + rlo) * 64 + (ks * 2 + kh) * 8);
        const int r0 = nbase + 4 * kh;
#pragma unroll
        for (int rg = 0; rg < 4; ++rg) aznc[rg] = *(const float4*)(azn + r0 + 8 * rg);
    }

#pragma unroll
    for (int tile = 0; tile < NTILES; ++tile) {
        short8 afn[4];
        float4 aznn[4];
        if (tile + 1 < NTILES) {
            const int nr = nbase + (tile + 1) * 128;
#pragma unroll
            for (int ks = 0; ks < 4; ++ks)
                afn[ks] = *(const short8*)(zTb + (size_t)(nr + rlo) * 64 + (ks * 2 + kh) * 8);
            const int r0 = nr + 4 * kh;
#pragma unroll
            for (int rg = 0; rg < 4; ++rg) aznn[rg] = *(const float4*)(azn + r0 + 8 * rg);
        }

        float azn_r[16];
#pragma unroll
        for (int rg = 0; rg < 4; ++rg) {
            azn_r[rg * 4 + 0] = aznc[rg].x; azn_r[rg * 4 + 1] = aznc[rg].y;
            azn_r[rg * 4 + 2] = aznc[rg].z; azn_r[rg * 4 + 3] = aznc[rg].w;
        }

        floatx16 acc[4];
#pragma unroll
        for (int mt = 0; mt < 4; ++mt)
#pragma unroll
            for (int r = 0; r < 16; ++r)
                acc[mt][r] = azn_r[r];           // aen factored out

#pragma unroll
        for (int ks = 0; ks < 4; ++ks)
#pragma unroll
            for (int mt = 0; mt < 4; ++mt)
                acc[mt] = __builtin_amdgcn_mfma_f32_32x32x16_bf16(
                    afc[ks], bf[mt][ks], acc[mt], 0, 0, 0);

#pragma unroll
        for (int mt = 0; mt < 4; ++mt) {
            float s = 0.f;
#pragma unroll
            for (int r = 0; r < 16; ++r) s += EXP2F(acc[mt][r]);
            sum[mt] += s;
        }

#pragma unroll
        for (int ks = 0; ks < 4; ++ks) afc[ks] = afn[ks];
#pragma unroll
        for (int rg = 0; rg < 4; ++rg) aznc[rg] = aznn[rg];
    }

#pragma unroll
    for (int mt = 0; mt < 4; ++mt) sum[mt] += __shfl_down(sum[mt], 32);

    if (t < BM) lds_red[t] = 0.f;
    __syncthreads();
    if (lane < 32) {
#pragma unroll
        for (int mt = 0; mt < 4; ++mt) atomicAdd(&lds_red[mt * 32 + rlo], sum[mt]);
    }
    __syncthreads();
    if (t < BM) atomicAdd(&sums[m0 + t], lds_red[t]);

    // ---- last-block ticket (no fences; see kernel comment) ----
    __syncthreads();          // drains vmcnt: all sums atomics of this block complete
    if (t == 0) {
        int old = atomicAdd((int*)(ws + TICK_OFF), 1);
        lastFlag = (old == NBLOCKS - 1);
    }
    __syncthreads();

    if (lastFlag) {
        const float* aen = ws + AEN_OFF;
        double local = 0.0;
#pragma unroll
        for (int j = 0; j < 16; ++j) {
            int m = t + 256 * j;
            float S = atomicAdd(&sums[m], 0.f);   // coherent read at memory-side point
            // lse_m = ln2 * (aen'_m + log2(S_m))
            local += (double)(aen[m] + log2f(S));
        }
        red[t] = local;
        __syncthreads();
        for (int off = 128; off > 0; off >>= 1) {
            if (t < off) red[t] += red[t + off];
            __syncthreads();
        }
        if (t == 0) {
            double ls = (double)lsp[0];
            double loss = -(LN2 * red[0] / (double)M_)
                          + 0.5 * (double)D_ * (2.0 * ls - 1.0)
                          + log((double)N_);
            out[0] = (float)loss;
        }
    }
}

extern "C" void kernel_launch(void* const* d_in, const int* in_sizes, int n_in,
                              void* d_out, int out_size, void* d_ws, size_t ws_size,
                              hipStream_t stream) {
    const float* z   = (const float*)d_in[0];
    const float* e   = (const float*)d_in[1];
    const float* lsp = (const float*)d_in[2];
    float* ws  = (float*)d_ws;
    float* out = (float*)d_out;

    hipLaunchKernelGGL(prep_kernel, dim3(272), dim3(256), 0, stream, z, e, lsp, ws);
    hipLaunchKernelGGL(main_fast, dim3(M_ / BM, NSPLIT), dim3(256), 0, stream,
                       ws, lsp, out);
}

// Round 4
// 77.391 us; speedup vs baseline: 1.4662x; 1.1395x over previous
//
#include <hip/hip_runtime.h>
#include <hip/hip_bf16.h>
#include <math.h>

#define D_   64
#define HW_  4096
#define N_   16384
#define M_   4096

// ---- geometry ----
#define BM 128                 // codes per block (e-rows register-resident)
#define NSPLIT 16              // n-splits across grid
#define NCHUNK (N_ / NSPLIT)   // 1024 rows per block
#define NTILES (NCHUNK / 128)  // 8 tiles of 128 rows (4 waves x 32)

// ---- ws layout (floats) ----
// zT/ebf are FRAGMENT-MAJOR: rows grouped by 32; within a group the eight
// 16B k-chunks are stored [ks][kh][row][16B] so a wave's MFMA-fragment load
// is base + lane*16 (one contiguous aligned 1KB transaction per load).
//   byte_off(row, chunk c=2ks+kh) = (row>>5)*4096 + (c>>1)*1024 + (c&1)*512 + (row&31)*16
#define AZN_OFF 0                      // azn'[16384]  (log2-domain row norms)
#define AEN_OFF 16384                  // aen'[4096]   (log2-domain col norms)
#define SUM_OFF 20480                  // sums[4096]
#define ZTB_OFF 24576                  // zT bf16 fragment-major, 2 MB
#define EBF_OFF (24576 + 524288)       // e  bf16 fragment-major, 0.5 MB
#define WS_FLOATS (EBF_OFF + 131072)

#define L2E 1.4426950408889634f
#define LN2 0.6931471805599453

typedef __attribute__((ext_vector_type(8))) short short8;
typedef __attribute__((ext_vector_type(16))) float floatx16;

#if __has_builtin(__builtin_amdgcn_exp2f)
#define EXP2F(x) __builtin_amdgcn_exp2f(x)
#else
#define EXP2F(x) exp2f(x)
#endif

__device__ __forceinline__ unsigned int bf16_rne(float x) {
    unsigned int u = __float_as_uint(x);
    u += 0x7fffu + ((u >> 16) & 1u);
    return u >> 16;
}

// blocks 0..255: z transpose+scale+norm ; blocks 256..271: e convert+norm+zero sums
__global__ void prep_kernel(const float* __restrict__ z,
                            const float* __restrict__ e,
                            const float* __restrict__ lsp,
                            float* __restrict__ ws) {
    const float ls = lsp[0];
    const float alpha = -0.5f * __expf(-2.f * ls);   // -1/(2 e^{2ls})
    const float anl = alpha * L2E;                   // norm scale (log2 domain)
    const float c2p = -2.f * alpha * L2E;            // z pre-scale (log2 domain)
    unsigned char* zTB = (unsigned char*)(ws + ZTB_OFF);
    unsigned char* eB  = (unsigned char*)(ws + EBF_OFF);
    const int blk = blockIdx.x, t = threadIdx.x;

    if (blk < 256) {
        __shared__ float lt[64 * 65];
        const int b = blk >> 6, hw0 = (blk & 63) * 64;
        const int n0 = b * HW_ + hw0;
        const float* zb = z + ((size_t)b * D_) * HW_ + hw0;
#pragma unroll
        for (int i = 0; i < 4; ++i) {
            int idx = t + 256 * i;
            int d = idx >> 4, c = (idx & 15) * 4;
            float4 v = *(const float4*)(zb + (size_t)d * HW_ + c);
            float* p = &lt[d * 65 + c];
            p[0] = v.x; p[1] = v.y; p[2] = v.z; p[3] = v.w;
        }
        __syncthreads();
#pragma unroll
        for (int j = 0; j < 2; ++j) {
            int idx = t + 256 * j;
            int nl = idx >> 3, c = idx & 7;    // row-in-tile, 16B k-chunk
            float v[8]; float s = 0.f;
#pragma unroll
            for (int jj = 0; jj < 8; ++jj) {
                v[jj] = lt[(8 * c + jj) * 65 + nl];
                s = fmaf(v[jj], v[jj], s);
            }
            s += __shfl_xor(s, 1);
            s += __shfl_xor(s, 2);
            s += __shfl_xor(s, 4);
            uint4 pk;
            pk.x = bf16_rne(v[0] * c2p) | (bf16_rne(v[1] * c2p) << 16);
            pk.y = bf16_rne(v[2] * c2p) | (bf16_rne(v[3] * c2p) << 16);
            pk.z = bf16_rne(v[4] * c2p) | (bf16_rne(v[5] * c2p) << 16);
            pk.w = bf16_rne(v[6] * c2p) | (bf16_rne(v[7] * c2p) << 16);
            const int n = n0 + nl;
            *(uint4*)(zTB + (size_t)(n >> 5) * 4096
                          + (c >> 1) * 1024 + (c & 1) * 512 + (n & 31) * 16) = pk;
            if (c == 0) ws[AZN_OFF + n] = anl * s;
        }
    } else {
        int m = (blk - 256) * 256 + t;
        const float4* ep = (const float4*)(e + (size_t)m * D_);
        float s = 0.f;
        unsigned int pk[32];
#pragma unroll
        for (int k = 0; k < 16; ++k) {
            float4 v = ep[k];
            s += v.x * v.x + v.y * v.y + v.z * v.z + v.w * v.w;
            pk[2 * k]     = bf16_rne(v.x) | (bf16_rne(v.y) << 16);
            pk[2 * k + 1] = bf16_rne(v.z) | (bf16_rne(v.w) << 16);
        }
        unsigned char* gb = eB + (size_t)(m >> 5) * 4096 + (m & 31) * 16;
#pragma unroll
        for (int c = 0; c < 8; ++c)
            *(uint4*)(gb + (c >> 1) * 1024 + (c & 1) * 512) =
                make_uint4(pk[4 * c], pk[4 * c + 1], pk[4 * c + 2], pk[4 * c + 3]);
        ws[AEN_OFF + m] = anl * s;
        ws[SUM_OFF + m] = 0.f;
    }
}

// grid (32,16), 256 thr: B (e, 128 rows) register-resident; 8 A-tiles of 128 rows
// with register double-buffer prefetch; aen factored OUT (added in finalize).
// All main-loop fragment loads are contiguous lane*16 (fragment-major layout).
__global__ __launch_bounds__(256, 2) void main_fast(float* __restrict__ ws) {
    __shared__ float lds_red[BM];
    const unsigned char* zTB = (const unsigned char*)(ws + ZTB_OFF);
    const unsigned char* eB  = (const unsigned char*)(ws + EBF_OFF);
    const float* azn = ws + AZN_OFF;
    float* sums = ws + SUM_OFF;

    const int m0 = blockIdx.x * BM;
    const int ns = blockIdx.y;
    const int t = threadIdx.x;
    const int lane = t & 63;
    const int w = t >> 6;
    const int rlo = lane & 31;
    const int kh = lane >> 5;

    // B fragments: 128 e-rows register-resident (64 VGPR); contiguous loads
    const unsigned char* ebase = eB + ((size_t)m0 >> 5) * 4096 + lane * 16;
    short8 bf[4][4];
#pragma unroll
    for (int mt = 0; mt < 4; ++mt)
#pragma unroll
        for (int ks = 0; ks < 4; ++ks)
            bf[mt][ks] = *(const short8*)(ebase + mt * 4096 + ks * 1024);

    float sum[4] = {0.f, 0.f, 0.f, 0.f};
    const int nbase = ns * NCHUNK + w * 32;
    const unsigned char* abase = zTB + ((size_t)nbase >> 5) * 4096 + lane * 16;

    // prefetch tile 0
    short8 afc[4];
    float4 aznc[4];
    {
#pragma unroll
        for (int ks = 0; ks < 4; ++ks)
            afc[ks] = *(const short8*)(abase + ks * 1024);
        const int r0 = nbase + 4 * kh;
#pragma unroll
        for (int rg = 0; rg < 4; ++rg) aznc[rg] = *(const float4*)(azn + r0 + 8 * rg);
    }

#pragma unroll
    for (int tile = 0; tile < NTILES; ++tile) {
        short8 afn[4];
        float4 aznn[4];
        if (tile + 1 < NTILES) {
            const unsigned char* ab = abase + (size_t)(tile + 1) * 16384;
#pragma unroll
            for (int ks = 0; ks < 4; ++ks)
                afn[ks] = *(const short8*)(ab + ks * 1024);
            const int r0 = nbase + (tile + 1) * 128 + 4 * kh;
#pragma unroll
            for (int rg = 0; rg < 4; ++rg) aznn[rg] = *(const float4*)(azn + r0 + 8 * rg);
        }

        float azn_r[16];
#pragma unroll
        for (int rg = 0; rg < 4; ++rg) {
            azn_r[rg * 4 + 0] = aznc[rg].x; azn_r[rg * 4 + 1] = aznc[rg].y;
            azn_r[rg * 4 + 2] = aznc[rg].z; azn_r[rg * 4 + 3] = aznc[rg].w;
        }

        floatx16 acc[4];
#pragma unroll
        for (int mt = 0; mt < 4; ++mt)
#pragma unroll
            for (int r = 0; r < 16; ++r)
                acc[mt][r] = azn_r[r];           // aen factored out

#pragma unroll
        for (int ks = 0; ks < 4; ++ks)
#pragma unroll
            for (int mt = 0; mt < 4; ++mt)
                acc[mt] = __builtin_amdgcn_mfma_f32_32x32x16_bf16(
                    afc[ks], bf[mt][ks], acc[mt], 0, 0, 0);

#pragma unroll
        for (int mt = 0; mt < 4; ++mt) {
            float s = 0.f;
#pragma unroll
            for (int r = 0; r < 16; ++r) s += EXP2F(acc[mt][r]);
            sum[mt] += s;
        }

#pragma unroll
        for (int ks = 0; ks < 4; ++ks) afc[ks] = afn[ks];
#pragma unroll
        for (int rg = 0; rg < 4; ++rg) aznc[rg] = aznn[rg];
    }

#pragma unroll
    for (int mt = 0; mt < 4; ++mt) sum[mt] += __shfl_down(sum[mt], 32);

    if (t < BM) lds_red[t] = 0.f;
    __syncthreads();
    if (lane < 32) {
#pragma unroll
        for (int mt = 0; mt < 4; ++mt) atomicAdd(&lds_red[mt * 32 + rlo], sum[mt]);
    }
    __syncthreads();
    if (t < BM) atomicAdd(&sums[m0 + t], lds_red[t]);
}

__global__ void finalize_fast(const float* __restrict__ ws,
                              const float* __restrict__ lsp,
                              float* __restrict__ out) {
    __shared__ double red[256];
    const float* sums = ws + SUM_OFF;
    const float* aen = ws + AEN_OFF;
    int t = threadIdx.x;
    double local = 0.0;
#pragma unroll
    for (int j = 0; j < 16; ++j) {
        int m = t + 256 * j;
        // lse_m = ln2 * (aen'_m + log2(S_m))
        local += (double)(aen[m] + log2f(sums[m]));
    }
    red[t] = local;
    __syncthreads();
    for (int off = 128; off > 0; off >>= 1) {
        if (t < off) red[t] += red[t + off];
        __syncthreads();
    }
    if (t == 0) {
        double ls = (double)lsp[0];
        double loss = -(LN2 * red[0] / (double)M_)
                      + 0.5 * (double)D_ * (2.0 * ls - 1.0)
                      + log((double)N_);
        out[0] = (float)loss;
    }
}

extern "C" void kernel_launch(void* const* d_in, const int* in_sizes, int n_in,
                              void* d_out, int out_size, void* d_ws, size_t ws_size,
                              hipStream_t stream) {
    const float* z   = (const float*)d_in[0];
    const float* e   = (const float*)d_in[1];
    const float* lsp = (const float*)d_in[2];
    float* ws  = (float*)d_ws;
    float* out = (float*)d_out;

    hipLaunchKernelGGL(prep_kernel, dim3(272), dim3(256), 0, stream, z, e, lsp, ws);
    hipLaunchKernelGGL(main_fast, dim3(M_ / BM, NSPLIT), dim3(256), 0, stream, ws);
    hipLaunchKernelGGL(finalize_fast, dim3(1), dim3(256), 0, stream, ws, lsp, out);
}

// Round 5
// 76.963 us; speedup vs baseline: 1.4744x; 1.0056x over previous
//
#include <hip/hip_runtime.h>
#include <hip/hip_bf16.h>
#include <math.h>

#define D_   64
#define HW_  4096
#define N_   16384
#define M_   4096

// ---- geometry ----
#define BM 128                 // codes per block (e-rows register-resident)
#define NSPLIT 32              // n-splits across grid (grid 1024 = 4 blocks/CU)
#define NCHUNK (N_ / NSPLIT)   // 512 rows per block
#define NTILES (NCHUNK / 128)  // 4 tiles of 128 rows (4 waves x 32)

// ---- ws layout (floats) ----
// zT/ebf are FRAGMENT-MAJOR: rows grouped by 32; within a group the eight
// 16B k-chunks are stored [ks][kh][row][16B] so a wave's MFMA-fragment load
// is base + lane*16 (one contiguous aligned 1KB transaction per load).
//   byte_off(row, chunk c=2ks+kh) = (row>>5)*4096 + (c>>1)*1024 + (c&1)*512 + (row&31)*16
#define AZN_OFF 0                      // azn'[16384]  (log2-domain row norms)
#define AEN_OFF 16384                  // aen'[4096]   (log2-domain col norms)
#define SUM_OFF 20480                  // sums[4096]
#define ZTB_OFF 24576                  // zT bf16 fragment-major, 2 MB
#define EBF_OFF (24576 + 524288)       // e  bf16 fragment-major, 0.5 MB
#define WS_FLOATS (EBF_OFF + 131072)

#define L2E 1.4426950408889634f
#define LN2 0.6931471805599453

typedef __attribute__((ext_vector_type(8))) short short8;
typedef __attribute__((ext_vector_type(16))) float floatx16;

#if __has_builtin(__builtin_amdgcn_exp2f)
#define EXP2F(x) __builtin_amdgcn_exp2f(x)
#else
#define EXP2F(x) exp2f(x)
#endif

__device__ __forceinline__ unsigned int bf16_rne(float x) {
    unsigned int u = __float_as_uint(x);
    u += 0x7fffu + ((u >> 16) & 1u);
    return u >> 16;
}

// blocks 0..255: z transpose+scale+norm ; blocks 256..271: e convert+norm+zero sums
__global__ void prep_kernel(const float* __restrict__ z,
                            const float* __restrict__ e,
                            const float* __restrict__ lsp,
                            float* __restrict__ ws) {
    const float ls = lsp[0];
    const float alpha = -0.5f * __expf(-2.f * ls);   // -1/(2 e^{2ls})
    const float anl = alpha * L2E;                   // norm scale (log2 domain)
    const float c2p = -2.f * alpha * L2E;            // z pre-scale (log2 domain)
    unsigned char* zTB = (unsigned char*)(ws + ZTB_OFF);
    unsigned char* eB  = (unsigned char*)(ws + EBF_OFF);
    const int blk = blockIdx.x, t = threadIdx.x;

    if (blk < 256) {
        __shared__ float lt[64 * 65];
        const int b = blk >> 6, hw0 = (blk & 63) * 64;
        const int n0 = b * HW_ + hw0;
        const float* zb = z + ((size_t)b * D_) * HW_ + hw0;
#pragma unroll
        for (int i = 0; i < 4; ++i) {
            int idx = t + 256 * i;
            int d = idx >> 4, c = (idx & 15) * 4;
            float4 v = *(const float4*)(zb + (size_t)d * HW_ + c);
            float* p = &lt[d * 65 + c];
            p[0] = v.x; p[1] = v.y; p[2] = v.z; p[3] = v.w;
        }
        __syncthreads();
#pragma unroll
        for (int j = 0; j < 2; ++j) {
            int idx = t + 256 * j;
            int nl = idx >> 3, c = idx & 7;    // row-in-tile, 16B k-chunk
            float v[8]; float s = 0.f;
#pragma unroll
            for (int jj = 0; jj < 8; ++jj) {
                v[jj] = lt[(8 * c + jj) * 65 + nl];
                s = fmaf(v[jj], v[jj], s);
            }
            s += __shfl_xor(s, 1);
            s += __shfl_xor(s, 2);
            s += __shfl_xor(s, 4);
            uint4 pk;
            pk.x = bf16_rne(v[0] * c2p) | (bf16_rne(v[1] * c2p) << 16);
            pk.y = bf16_rne(v[2] * c2p) | (bf16_rne(v[3] * c2p) << 16);
            pk.z = bf16_rne(v[4] * c2p) | (bf16_rne(v[5] * c2p) << 16);
            pk.w = bf16_rne(v[6] * c2p) | (bf16_rne(v[7] * c2p) << 16);
            const int n = n0 + nl;
            *(uint4*)(zTB + (size_t)(n >> 5) * 4096
                          + (c >> 1) * 1024 + (c & 1) * 512 + (n & 31) * 16) = pk;
            if (c == 0) ws[AZN_OFF + n] = anl * s;
        }
    } else {
        int m = (blk - 256) * 256 + t;
        const float4* ep = (const float4*)(e + (size_t)m * D_);
        float s = 0.f;
        unsigned int pk[32];
#pragma unroll
        for (int k = 0; k < 16; ++k) {
            float4 v = ep[k];
            s += v.x * v.x + v.y * v.y + v.z * v.z + v.w * v.w;
            pk[2 * k]     = bf16_rne(v.x) | (bf16_rne(v.y) << 16);
            pk[2 * k + 1] = bf16_rne(v.z) | (bf16_rne(v.w) << 16);
        }
        unsigned char* gb = eB + (size_t)(m >> 5) * 4096 + (m & 31) * 16;
#pragma unroll
        for (int c = 0; c < 8; ++c)
            *(uint4*)(gb + (c >> 1) * 1024 + (c & 1) * 512) =
                make_uint4(pk[4 * c], pk[4 * c + 1], pk[4 * c + 2], pk[4 * c + 3]);
        ws[AEN_OFF + m] = anl * s;
        ws[SUM_OFF + m] = 0.f;
    }
}

// grid (32,32), 256 thr: B (e, 128 rows) register-resident; 4 A-tiles of 128 rows
// with register double-buffer prefetch; aen factored OUT (added in finalize).
// All main-loop fragment loads are contiguous lane*16 (fragment-major layout).
// VGPR=112 -> 4 waves/SIMD possible; grid 1024 = 4 blocks/CU co-resident.
__global__ __launch_bounds__(256, 2) void main_fast(float* __restrict__ ws) {
    __shared__ float lds_red[BM];
    const unsigned char* zTB = (const unsigned char*)(ws + ZTB_OFF);
    const unsigned char* eB  = (const unsigned char*)(ws + EBF_OFF);
    const float* azn = ws + AZN_OFF;
    float* sums = ws + SUM_OFF;

    const int m0 = blockIdx.x * BM;
    const int ns = blockIdx.y;
    const int t = threadIdx.x;
    const int lane = t & 63;
    const int w = t >> 6;
    const int rlo = lane & 31;
    const int kh = lane >> 5;

    // B fragments: 128 e-rows register-resident (64 VGPR); contiguous loads
    const unsigned char* ebase = eB + ((size_t)m0 >> 5) * 4096 + lane * 16;
    short8 bf[4][4];
#pragma unroll
    for (int mt = 0; mt < 4; ++mt)
#pragma unroll
        for (int ks = 0; ks < 4; ++ks)
            bf[mt][ks] = *(const short8*)(ebase + mt * 4096 + ks * 1024);

    float sum[4] = {0.f, 0.f, 0.f, 0.f};
    const int nbase = ns * NCHUNK + w * 32;
    const unsigned char* abase = zTB + ((size_t)nbase >> 5) * 4096 + lane * 16;

    // prefetch tile 0
    short8 afc[4];
    float4 aznc[4];
    {
#pragma unroll
        for (int ks = 0; ks < 4; ++ks)
            afc[ks] = *(const short8*)(abase + ks * 1024);
        const int r0 = nbase + 4 * kh;
#pragma unroll
        for (int rg = 0; rg < 4; ++rg) aznc[rg] = *(const float4*)(azn + r0 + 8 * rg);
    }

#pragma unroll
    for (int tile = 0; tile < NTILES; ++tile) {
        short8 afn[4];
        float4 aznn[4];
        if (tile + 1 < NTILES) {
            const unsigned char* ab = abase + (size_t)(tile + 1) * 16384;
#pragma unroll
            for (int ks = 0; ks < 4; ++ks)
                afn[ks] = *(const short8*)(ab + ks * 1024);
            const int r0 = nbase + (tile + 1) * 128 + 4 * kh;
#pragma unroll
            for (int rg = 0; rg < 4; ++rg) aznn[rg] = *(const float4*)(azn + r0 + 8 * rg);
        }

        float azn_r[16];
#pragma unroll
        for (int rg = 0; rg < 4; ++rg) {
            azn_r[rg * 4 + 0] = aznc[rg].x; azn_r[rg * 4 + 1] = aznc[rg].y;
            azn_r[rg * 4 + 2] = aznc[rg].z; azn_r[rg * 4 + 3] = aznc[rg].w;
        }

        floatx16 acc[4];
#pragma unroll
        for (int mt = 0; mt < 4; ++mt)
#pragma unroll
            for (int r = 0; r < 16; ++r)
                acc[mt][r] = azn_r[r];           // aen factored out

#pragma unroll
        for (int ks = 0; ks < 4; ++ks)
#pragma unroll
            for (int mt = 0; mt < 4; ++mt)
                acc[mt] = __builtin_amdgcn_mfma_f32_32x32x16_bf16(
                    afc[ks], bf[mt][ks], acc[mt], 0, 0, 0);

#pragma unroll
        for (int mt = 0; mt < 4; ++mt) {
            float s = 0.f;
#pragma unroll
            for (int r = 0; r < 16; ++r) s += EXP2F(acc[mt][r]);
            sum[mt] += s;
        }

#pragma unroll
        for (int ks = 0; ks < 4; ++ks) afc[ks] = afn[ks];
#pragma unroll
        for (int rg = 0; rg < 4; ++rg) aznc[rg] = aznn[rg];
    }

#pragma unroll
    for (int mt = 0; mt < 4; ++mt) sum[mt] += __shfl_down(sum[mt], 32);

    if (t < BM) lds_red[t] = 0.f;
    __syncthreads();
    if (lane < 32) {
#pragma unroll
        for (int mt = 0; mt < 4; ++mt) atomicAdd(&lds_red[mt * 32 + rlo], sum[mt]);
    }
    __syncthreads();
    if (t < BM) atomicAdd(&sums[m0 + t], lds_red[t]);
}

__global__ void finalize_fast(const float* __restrict__ ws,
                              const float* __restrict__ lsp,
                              float* __restrict__ out) {
    __shared__ double red[256];
    const float* sums = ws + SUM_OFF;
    const float* aen = ws + AEN_OFF;
    int t = threadIdx.x;
    double local = 0.0;
#pragma unroll
    for (int j = 0; j < 16; ++j) {
        int m = t + 256 * j;
        // lse_m = ln2 * (aen'_m + log2(S_m))
        local += (double)(aen[m] + log2f(sums[m]));
    }
    red[t] = local;
    __syncthreads();
    for (int off = 128; off > 0; off >>= 1) {
        if (t < off) red[t] += red[t + off];
        __syncthreads();
    }
    if (t == 0) {
        double ls = (double)lsp[0];
        double loss = -(LN2 * red[0] / (double)M_)
                      + 0.5 * (double)D_ * (2.0 * ls - 1.0)
                      + log((double)N_);
        out[0] = (float)loss;
    }
}

extern "C" void kernel_launch(void* const* d_in, const int* in_sizes, int n_in,
                              void* d_out, int out_size, void* d_ws, size_t ws_size,
                              hipStream_t stream) {
    const float* z   = (const float*)d_in[0];
    const float* e   = (const float*)d_in[1];
    const float* lsp = (const float*)d_in[2];
    float* ws  = (float*)d_ws;
    float* out = (float*)d_out;

    hipLaunchKernelGGL(prep_kernel, dim3(272), dim3(256), 0, stream, z, e, lsp, ws);
    hipLaunchKernelGGL(main_fast, dim3(M_ / BM, NSPLIT), dim3(256), 0, stream, ws);
    hipLaunchKernelGGL(finalize_fast, dim3(1), dim3(256), 0, stream, ws, lsp, out);
}